// Round 10
// baseline (4174.525 us; speedup 1.0000x reference)
//
#include <hip/hip_runtime.h>
#include <math.h>

#define TPF 36
#define KFRM 4
#define DM 1024
#define NH 16
#define HD 64
#define NLAYER 8
#define VOCAB 4096
#define SEQ 184
#define BATCH 64
#define NTOK (BATCH * SEQ)   // 11776
#define CTXEND 148

typedef unsigned short u16;
typedef unsigned int u32;
typedef __bf16 bf16x8 __attribute__((ext_vector_type(8)));
typedef float f32x4 __attribute__((ext_vector_type(4)));

struct alignas(8) U16x4 { u16 x, y, z, w; };
struct alignas(16) U16x8 { u16 v[8]; };

__device__ inline u16 f2b(float f) {
  u32 u = __float_as_uint(f);
  u += 0x7FFFu + ((u >> 16) & 1u);
  return (u16)(u >> 16);
}
__device__ inline float b2f(u16 h) { return __uint_as_float(((u32)h) << 16); }

// ---------------- f32 -> bf16 conversion ----------------
__global__ __launch_bounds__(256) void conv_bf16(const float4* __restrict__ in,
                                                 U16x4* __restrict__ out, int n4) {
  int i = blockIdx.x * 256 + threadIdx.x;
  if (i >= n4) return;
  float4 v = in[i];
  U16x4 o;
  o.x = f2b(v.x); o.y = f2b(v.y); o.z = f2b(v.z); o.w = f2b(v.w);
  out[i] = o;
}

// fused per-layer conversion: qkv_w + out_w + mlp_w1 + mlp_w2 in one dispatch
#define CN1 (3072 * 1024 / 4)
#define CN2 (1024 * 1024 / 4)
#define CN3 (4096 * 1024 / 4)
__global__ __launch_bounds__(256) void conv_layer(
    const float4* __restrict__ s1, U16x4* __restrict__ d1,
    const float4* __restrict__ s2, U16x4* __restrict__ d2,
    const float4* __restrict__ s3, U16x4* __restrict__ d3,
    const float4* __restrict__ s4, U16x4* __restrict__ d4) {
  int j = blockIdx.x * 256 + threadIdx.x;
  const float4* s; U16x4* d;
  if (j < CN1) { s = s1; d = d1; }
  else if ((j -= CN1) < CN2) { s = s2; d = d2; }
  else if ((j -= CN2) < CN3) { s = s3; d = d3; }
  else { j -= CN3; s = s4; d = d4; }
  float4 v = s[j];
  U16x4 o;
  o.x = f2b(v.x); o.y = f2b(v.y); o.z = f2b(v.z); o.w = f2b(v.w);
  d[j] = o;
}

// ---------------- embedding ----------------
__global__ __launch_bounds__(256) void embed_kernel(
    const int* __restrict__ ft, const int* __restrict__ act, const int* __restrict__ lvl,
    const float* __restrict__ tok_emb, const float* __restrict__ act_emb,
    const float* __restrict__ lvl_emb, float* __restrict__ x) {
  int row = blockIdx.x;
  int b = row / SEQ, s = row % SEQ;
  const float* src;
  if (s < CTXEND) {
    int i = s / 37, r = s % 37;
    if (r < 36) src = tok_emb + (size_t)ft[(b * 5 + i) * TPF + r] * DM;
    else        src = act_emb + (size_t)act[b * KFRM + i] * DM;
  } else {
    src = tok_emb + (size_t)ft[(b * 5 + 4) * TPF + (s - CTXEND)] * DM;
  }
  const float* le = lvl_emb + (size_t)lvl[b] * DM;
  float* dst = x + (size_t)row * DM;
  for (int d = threadIdx.x; d < DM; d += 256) dst[d] = src[d] + le[d];
}

// ---------------- LayerNorm (f32 in -> bf16 out), one wave per row ----------------
__global__ __launch_bounds__(256) void ln_rows(const float* __restrict__ x,
    const float* __restrict__ g, const float* __restrict__ bb,
    u16* __restrict__ out, int nrows) {
  int wid = blockIdx.x * 4 + (threadIdx.x >> 6);
  if (wid >= nrows) return;
  int lane = threadIdx.x & 63;
  const float* row = x + (size_t)wid * DM;
  float s = 0.f, ss = 0.f;
  float v[16];
#pragma unroll
  for (int i = 0; i < 16; i++) {
    v[i] = row[i * 64 + lane];
    s += v[i]; ss += v[i] * v[i];
  }
#pragma unroll
  for (int m = 32; m; m >>= 1) { s += __shfl_xor(s, m, 64); ss += __shfl_xor(ss, m, 64); }
  float mean = s * (1.f / DM);
  float var = ss * (1.f / DM) - mean * mean;
  float rstd = rsqrtf(var + 1e-5f);
  u16* dst = out + (size_t)wid * DM;
#pragma unroll
  for (int i = 0; i < 16; i++) {
    int d = i * 64 + lane;
    dst[d] = f2b((v[i] - mean) * rstd * g[d] + bb[d]);
  }
}

// ---------------- final LN: gather predict rows (bf16) + row 183 (f32) ----------------
__global__ __launch_bounds__(256) void lnf_kernel(const float* __restrict__ x,
    const float* __restrict__ g, const float* __restrict__ bb,
    u16* __restrict__ pred, float* __restrict__ r183) {
  int wid = blockIdx.x * 4 + (threadIdx.x >> 6);
  if (wid >= BATCH * 37) return;
  int lane = threadIdx.x & 63;
  int b = wid / 37, si = wid % 37, s = 147 + si;
  const float* row = x + ((size_t)b * SEQ + s) * DM;
  float sum = 0.f, ss = 0.f;
  float v[16];
#pragma unroll
  for (int i = 0; i < 16; i++) {
    v[i] = row[i * 64 + lane];
    sum += v[i]; ss += v[i] * v[i];
  }
#pragma unroll
  for (int m = 32; m; m >>= 1) { sum += __shfl_xor(sum, m, 64); ss += __shfl_xor(ss, m, 64); }
  float mean = sum * (1.f / DM);
  float var = ss * (1.f / DM) - mean * mean;
  float rstd = rsqrtf(var + 1e-5f);
  if (s < 183) {
    u16* dst = pred + ((size_t)b * 36 + si) * DM;
#pragma unroll
    for (int i = 0; i < 16; i++) {
      int d = i * 64 + lane;
      dst[d] = f2b((v[i] - mean) * rstd * g[d] + bb[d]);
    }
  } else {
    float* dst = r183 + (size_t)b * DM;
#pragma unroll
    for (int i = 0; i < 16; i++) {
      int d = i * 64 + lane;
      dst[d] = (v[i] - mean) * rstd * g[d] + bb[d];
    }
  }
}

// ---------------- 256x256 bf16 NT GEMM (BK=64, 16 waves, SINGLE-buffer LDS, swizzled) --
// C[n,m] = sum_k A[n,k]*W[m,k]
// 64 KiB LDS -> 2 blocks/CU -> up to 8 waves/SIMD; cross-block overlap hides the
// stage->barrier drain (m97/m114 regime). 16 waves, each a 64x64 output sub-tile.
// MODE 0: bf16 out = acc + bias | 1: f32 += acc+bias | 2: bf16 gelu(acc+bias) | 3: f32 = acc
__device__ inline void gld_lds16(const void* g, void* l) {
  __builtin_amdgcn_global_load_lds((const __attribute__((address_space(1))) void*)g,
                                   (__attribute__((address_space(3))) void*)l, 16, 0, 0);
}

// LDS tile: logical [256 rows][128 bytes]; physical = logical ^ (((o>>7)&7)<<4).

template <int MODE>
__global__ __launch_bounds__(1024) void gemm16(
    const u16* __restrict__ A, const u16* __restrict__ W,
    const float* __restrict__ bias, float* __restrict__ Cf, u16* __restrict__ Cb,
    int M, int Kdim) {
  __shared__ alignas(16) char As[32768];
  __shared__ alignas(16) char Bs[32768];
  const int tid = threadIdx.x;
  const int wave = tid >> 6, lane = tid & 63;
  const int wm = wave >> 2, wn = wave & 3;
  const int lr = lane & 15, g = lane >> 4;

  // XCD-chunked block swizzle (all grids here have nwg % 8 == 0)
  const int nbx = gridDim.x;
  int nwg = gridDim.x * gridDim.y;
  int id = blockIdx.y * gridDim.x + blockIdx.x;
  int id2 = (id & 7) * (nwg >> 3) + (id >> 3);
  const int row0 = (id2 / nbx) * 256, col0 = (id2 % nbx) * 256;

  const size_t krow = (size_t)Kdim * 2;  // bytes per logical row
  const char* Abase = (const char*)A + (size_t)row0 * krow;
  const char* Wbase = (const char*)W + (size_t)col0 * krow;

  auto stage = [&](int t) {
    const char* Ab = Abase + (size_t)t * 128;
    const char* Wb = Wbase + (size_t)t * 128;
#pragma unroll
    for (int c = 0; c < 2; c++) {
      int ob = wave * 2048 + c * 1024;      // wave-uniform LDS base (linear dest)
      int o = ob + lane * 16;               // this lane's implicit dest
      int os = o ^ (((o >> 7) & 7) << 4);   // inverse-swizzled logical source
      gld_lds16(Ab + (size_t)(os >> 7) * krow + (os & 127), &As[ob]);
      gld_lds16(Wb + (size_t)(os >> 7) * krow + (os & 127), &Bs[ob]);
    }
  };

  const int NT = Kdim >> 6;
  f32x4 acc[4][4] = {};

#pragma unroll 1
  for (int t = 0; t < NT; t++) {
    stage(t);
    __syncthreads();
#pragma unroll
    for (int kk = 0; kk < 2; kk++) {
      bf16x8 af[4], bfj[4];
#pragma unroll
      for (int i = 0; i < 4; i++) {
        int r = wm * 64 + i * 16 + lr;
        int o = r * 128 + kk * 64 + g * 16;
        af[i] = *(const bf16x8*)(As + (o ^ ((r & 7) << 4)));
      }
#pragma unroll
      for (int j = 0; j < 4; j++) {
        int r = wn * 64 + j * 16 + lr;
        int o = r * 128 + kk * 64 + g * 16;
        bfj[j] = *(const bf16x8*)(Bs + (o ^ ((r & 7) << 4)));
      }
#pragma unroll
      for (int i = 0; i < 4; i++)
#pragma unroll
        for (int j = 0; j < 4; j++)
          acc[i][j] = __builtin_amdgcn_mfma_f32_16x16x32_bf16(af[i], bfj[j], acc[i][j], 0, 0, 0);
    }
    __syncthreads();
  }

  // epilogue
  float bj[4];
  if (MODE != 3) {
#pragma unroll
    for (int j = 0; j < 4; j++) bj[j] = bias[col0 + wn * 64 + j * 16 + lr];
  }
#pragma unroll
  for (int i = 0; i < 4; i++) {
#pragma unroll
    for (int j = 0; j < 4; j++) {
#pragma unroll
      for (int r = 0; r < 4; r++) {
        int grow = row0 + wm * 64 + i * 16 + g * 4 + r;
        int gcol = col0 + wn * 64 + j * 16 + lr;
        float v = acc[i][j][r];
        size_t idx = (size_t)grow * M + gcol;
        if (MODE == 0) { v += bj[j]; Cb[idx] = f2b(v); }
        else if (MODE == 1) { v += bj[j]; Cf[idx] += v; }
        else if (MODE == 2) {
          v += bj[j];
          // tanh-form GELU: x*sigmoid(1.5957692*(x+0.044715x^3)), |err|<~7e-4
          float z = 1.5957692f * (v + 0.044715f * v * v * v);
          v = v / (1.f + __expf(-z));
          Cb[idx] = f2b(v);
        } else {
          Cf[idx] = v;
        }
      }
    }
  }
}

// ---------------- MFMA attention ----------------
#define SP 192
#define KST 72
#define VST 200
#define PST 200

__device__ inline int block_of(int s) {
  return (s < CTXEND) ? (2 * (s / 37) + ((s % 37) == 36)) : 8;
}

__global__ __launch_bounds__(256) void attn_mfma(const u16* __restrict__ qkv,
    u16* __restrict__ outb, const float* __restrict__ rc, const float* __restrict__ rs) {
  __shared__ alignas(16) u16 Ks[SP][KST];
  __shared__ alignas(16) u16 Vt[HD][VST];
  __shared__ alignas(16) u16 Ps[4][16][PST];
  const int b = blockIdx.x >> 4, h = blockIdx.x & 15;
  const int tid = threadIdx.x, wave = tid >> 6, lane = tid & 63;
  const int lr = lane & 15, g = lane >> 4, g4 = g * 4;
  const u16* base = qkv + (size_t)b * SEQ * 3072 + h * HD;

  for (int idx = tid; idx < SP * 32; idx += 256) {
    int s = idx >> 5, d = idx & 31;
    if (s < SEQ) {
      const u16* kr = base + (size_t)s * 3072 + 1024;
      float x1 = b2f(kr[d]), x2 = b2f(kr[d + 32]);
      float c = rc[s * 32 + d], sn = rs[s * 32 + d];
      Ks[s][d] = f2b(x1 * c - x2 * sn);
      Ks[s][d + 32] = f2b(x1 * sn + x2 * c);
    } else {
      Ks[s][d] = 0;
      Ks[s][d + 32] = 0;
    }
  }
  for (int idx = tid; idx < SP * HD; idx += 256) {
    int k = idx >> 6, d = idx & 63;
    Vt[d][k] = (k < SEQ) ? base[(size_t)k * 3072 + 2048 + d] : (u16)0;
  }
  __syncthreads();

#pragma unroll 1
  for (int t = 0; t < 3; t++) {
    const int q0 = (wave + 4 * t) * 16;
    const int q_lane = q0 + lr;
    const int qc = (q_lane < SEQ) ? q_lane : (SEQ - 1);

    U16x8 raw0 = *(const U16x8*)(base + (size_t)qc * 3072 + g * 8);
    U16x8 raw1 = *(const U16x8*)(base + (size_t)qc * 3072 + 32 + g * 8);
    bf16x8 qa0, qa1;
#pragma unroll
    for (int i = 0; i < 8; i++) {
      float x1 = b2f(raw0.v[i]), x2 = b2f(raw1.v[i]);
      int di = g * 8 + i;
      float c = rc[qc * 32 + di], sn = rs[qc * 32 + di];
      qa0[i] = (__bf16)(x1 * c - x2 * sn);
      qa1[i] = (__bf16)(x1 * sn + x2 * c);
    }

    f32x4 accs[12];
#pragma unroll
    for (int kt = 0; kt < 12; kt++) accs[kt] = (f32x4){0.f, 0.f, 0.f, 0.f};
#pragma unroll
    for (int kt = 0; kt < 12; kt++) {
      bf16x8 kb0 = *(const bf16x8*)&Ks[kt * 16 + lr][g * 8];
      bf16x8 kb1 = *(const bf16x8*)&Ks[kt * 16 + lr][32 + g * 8];
      accs[kt] = __builtin_amdgcn_mfma_f32_16x16x32_bf16(qa0, kb0, accs[kt], 0, 0, 0);
      accs[kt] = __builtin_amdgcn_mfma_f32_16x16x32_bf16(qa1, kb1, accs[kt], 0, 0, 0);
    }

    int qb[4];
#pragma unroll
    for (int r = 0; r < 4; r++) qb[r] = block_of(q0 + g4 + r);
    float mr[4] = {-3e38f, -3e38f, -3e38f, -3e38f};
#pragma unroll
    for (int kt = 0; kt < 12; kt++) {
      int k = kt * 16 + lr;
      bool kv = k < SEQ;
      int kb = kv ? block_of(k) : 9;
#pragma unroll
      for (int r = 0; r < 4; r++) {
        int q = q0 + g4 + r;
        bool ok = kv && (kb <= qb[r]) && !(q >= CTXEND && k >= CTXEND && k > q);
        float s = ok ? accs[kt][r] * 0.125f : -3e38f;
        accs[kt][r] = s;
        mr[r] = fmaxf(mr[r], s);
      }
    }
#pragma unroll
    for (int m = 1; m <= 8; m <<= 1)
#pragma unroll
      for (int r = 0; r < 4; r++) mr[r] = fmaxf(mr[r], __shfl_xor(mr[r], m, 64));

    float sr[4] = {0.f, 0.f, 0.f, 0.f};
#pragma unroll
    for (int kt = 0; kt < 12; kt++) {
#pragma unroll
      for (int r = 0; r < 4; r++) {
        float e = (accs[kt][r] > -1e37f) ? __expf(accs[kt][r] - mr[r]) : 0.f;
        Ps[wave][g4 + r][kt * 16 + lr] = f2b(e);
        sr[r] += e;
      }
    }
#pragma unroll
    for (int m = 1; m <= 8; m <<= 1)
#pragma unroll
      for (int r = 0; r < 4; r++) sr[r] += __shfl_xor(sr[r], m, 64);
    float inv[4];
#pragma unroll
    for (int r = 0; r < 4; r++) inv[r] = 1.f / sr[r];

    __builtin_amdgcn_s_waitcnt(0);

    f32x4 acco[4];
#pragma unroll
    for (int dt = 0; dt < 4; dt++) acco[dt] = (f32x4){0.f, 0.f, 0.f, 0.f};
#pragma unroll
    for (int kc = 0; kc < 6; kc++) {
      bf16x8 pa = *(const bf16x8*)&Ps[wave][lr][kc * 32 + g * 8];
#pragma unroll
      for (int dt = 0; dt < 4; dt++) {
        bf16x8 vb = *(const bf16x8*)&Vt[dt * 16 + lr][kc * 32 + g * 8];
        acco[dt] = __builtin_amdgcn_mfma_f32_16x16x32_bf16(pa, vb, acco[dt], 0, 0, 0);
      }
    }

#pragma unroll
    for (int dt = 0; dt < 4; dt++) {
#pragma unroll
      for (int r = 0; r < 4; r++) {
        int q = q0 + g4 + r;
        if (q < SEQ)
          outb[((size_t)b * SEQ + q) * DM + h * HD + dt * 16 + lr] = f2b(acco[dt][r] * inv[r]);
      }
    }
  }
}

// ---------------- death logit ----------------
__global__ void death_kernel(const float* __restrict__ r183, const float* __restrict__ dw,
                             const float* __restrict__ db, float* __restrict__ out) {
  int b = blockIdx.x, lane = threadIdx.x;
  float a = 0.f;
  for (int d = lane; d < DM; d += 64) a += r183[(size_t)b * DM + d] * dw[d];
#pragma unroll
  for (int m = 32; m; m >>= 1) a += __shfl_xor(a, m, 64);
  if (lane == 0) out[(size_t)BATCH * TPF * VOCAB + b] = a + db[0];
}

extern "C" void kernel_launch(void* const* d_in, const int* in_sizes, int n_in,
                              void* d_out, int out_size, void* d_ws, size_t ws_size,
                              hipStream_t stream) {
  const int* ft = (const int*)d_in[0];
  const int* act = (const int*)d_in[1];
  const int* lvl = (const int*)d_in[2];
  const float* tok_emb = (const float*)d_in[3];
  const float* act_emb = (const float*)d_in[4];
  const float* lvl_emb = (const float*)d_in[5];
  const float* ln1_g = (const float*)d_in[6];
  const float* ln1_b = (const float*)d_in[7];
  const float* qkv_w = (const float*)d_in[8];
  const float* qkv_b = (const float*)d_in[9];
  const float* out_w = (const float*)d_in[10];
  const float* out_b = (const float*)d_in[11];
  const float* ln2_g = (const float*)d_in[12];
  const float* ln2_b = (const float*)d_in[13];
  const float* mlp_w1 = (const float*)d_in[14];
  const float* mlp_b1 = (const float*)d_in[15];
  const float* mlp_w2 = (const float*)d_in[16];
  const float* mlp_b2 = (const float*)d_in[17];
  const float* lnf_g = (const float*)d_in[18];
  const float* lnf_b = (const float*)d_in[19];
  const float* head_w = (const float*)d_in[20];
  const float* death_w = (const float*)d_in[21];
  const float* death_b = (const float*)d_in[22];
  const float* rope_cos = (const float*)d_in[23];
  const float* rope_sin = (const float*)d_in[24];

  char* ws = (char*)d_ws;
  size_t off = 0;
  auto alloc = [&](size_t bytes) {
    void* p = ws + off;
    off += (bytes + 255) & ~(size_t)255;
    return p;
  };
  float* x   = (float*)alloc((size_t)NTOK * DM * 4);
  u16* hb    = (u16*)alloc((size_t)NTOK * DM * 2);
  u16* big   = (u16*)alloc((size_t)NTOK * 4096 * 2);
  u16* wq    = (u16*)alloc((size_t)3072 * 1024 * 2);
  u16* wo    = (u16*)alloc((size_t)1024 * 1024 * 2);
  u16* w1    = (u16*)alloc((size_t)4096 * 1024 * 2);
  u16* w2    = (u16*)alloc((size_t)4096 * 1024 * 2);
  u16* pred  = (u16*)alloc((size_t)BATCH * 36 * DM * 2);
  float* r183 = (float*)alloc((size_t)BATCH * DM * 4);

  float* out = (float*)d_out;

  embed_kernel<<<NTOK, 256, 0, stream>>>(ft, act, lvl, tok_emb, act_emb, lvl_emb, x);

  for (int l = 0; l < NLAYER; l++) {
    conv_layer<<<(CN1 + CN2 + 2 * CN3) / 256, 256, 0, stream>>>(
        (const float4*)(qkv_w + (size_t)l * 3072 * 1024), (U16x4*)wq,
        (const float4*)(out_w + (size_t)l * 1024 * 1024), (U16x4*)wo,
        (const float4*)(mlp_w1 + (size_t)l * 4096 * 1024), (U16x4*)w1,
        (const float4*)(mlp_w2 + (size_t)l * 4096 * 1024), (U16x4*)w2);

    ln_rows<<<NTOK / 4, 256, 0, stream>>>(x, ln1_g + l * DM, ln1_b + l * DM, hb, NTOK);
    gemm16<0><<<dim3(3072 / 256, NTOK / 256), 1024, 0, stream>>>(
        hb, wq, qkv_b + (size_t)l * 3072, nullptr, big, 3072, 1024);
    attn_mfma<<<BATCH * NH, 256, 0, stream>>>(big, hb, rope_cos, rope_sin);
    gemm16<1><<<dim3(1024 / 256, NTOK / 256), 1024, 0, stream>>>(
        hb, wo, out_b + (size_t)l * DM, x, nullptr, 1024, 1024);
    ln_rows<<<NTOK / 4, 256, 0, stream>>>(x, ln2_g + l * DM, ln2_b + l * DM, hb, NTOK);
    gemm16<2><<<dim3(4096 / 256, NTOK / 256), 1024, 0, stream>>>(
        hb, w1, mlp_b1 + (size_t)l * 4096, nullptr, big, 4096, 1024);
    gemm16<1><<<dim3(1024 / 256, NTOK / 256), 1024, 0, stream>>>(
        big, w2, mlp_b2 + (size_t)l * DM, x, nullptr, 1024, 4096);
  }

  lnf_kernel<<<BATCH * 37 / 4, 256, 0, stream>>>(x, lnf_g, lnf_b, pred, r183);
  conv_bf16<<<4096 * 1024 / 4 / 256, 256, 0, stream>>>(
      (const float4*)head_w, (U16x4*)w1, 4096 * 1024 / 4);
  gemm16<3><<<dim3(4096 / 256, BATCH * 36 / 256), 1024, 0, stream>>>(
      pred, w1, nullptr, out, nullptr, 4096, 1024);
  death_kernel<<<BATCH, 64, 0, stream>>>(r183, death_w, death_b, out);
}

// Round 11
// 4168.363 us; speedup vs baseline: 1.0015x; 1.0015x over previous
//
#include <hip/hip_runtime.h>
#include <math.h>

#define TPF 36
#define KFRM 4
#define DM 1024
#define NH 16
#define HD 64
#define NLAYER 8
#define VOCAB 4096
#define SEQ 184
#define BATCH 64
#define NTOK (BATCH * SEQ)   // 11776
#define CTXEND 148

typedef unsigned short u16;
typedef unsigned int u32;
typedef __bf16 bf16x8 __attribute__((ext_vector_type(8)));
typedef float f32x4 __attribute__((ext_vector_type(4)));

struct alignas(8) U16x4 { u16 x, y, z, w; };
struct alignas(16) U16x8 { u16 v[8]; };

__device__ inline u16 f2b(float f) {
  u32 u = __float_as_uint(f);
  u += 0x7FFFu + ((u >> 16) & 1u);
  return (u16)(u >> 16);
}
__device__ inline float b2f(u16 h) { return __uint_as_float(((u32)h) << 16); }

// ---------------- f32 -> bf16 conversion ----------------
__global__ __launch_bounds__(256) void conv_bf16(const float4* __restrict__ in,
                                                 U16x4* __restrict__ out, int n4) {
  int i = blockIdx.x * 256 + threadIdx.x;
  if (i >= n4) return;
  float4 v = in[i];
  U16x4 o;
  o.x = f2b(v.x); o.y = f2b(v.y); o.z = f2b(v.z); o.w = f2b(v.w);
  out[i] = o;
}

// fused per-layer conversion: qkv_w + out_w + mlp_w1 + mlp_w2 in one dispatch
#define CN1 (3072 * 1024 / 4)
#define CN2 (1024 * 1024 / 4)
#define CN3 (4096 * 1024 / 4)
__global__ __launch_bounds__(256) void conv_layer(
    const float4* __restrict__ s1, U16x4* __restrict__ d1,
    const float4* __restrict__ s2, U16x4* __restrict__ d2,
    const float4* __restrict__ s3, U16x4* __restrict__ d3,
    const float4* __restrict__ s4, U16x4* __restrict__ d4) {
  int j = blockIdx.x * 256 + threadIdx.x;
  const float4* s; U16x4* d;
  if (j < CN1) { s = s1; d = d1; }
  else if ((j -= CN1) < CN2) { s = s2; d = d2; }
  else if ((j -= CN2) < CN3) { s = s3; d = d3; }
  else { j -= CN3; s = s4; d = d4; }
  float4 v = s[j];
  U16x4 o;
  o.x = f2b(v.x); o.y = f2b(v.y); o.z = f2b(v.z); o.w = f2b(v.w);
  d[j] = o;
}

// ---------------- embedding ----------------
__global__ __launch_bounds__(256) void embed_kernel(
    const int* __restrict__ ft, const int* __restrict__ act, const int* __restrict__ lvl,
    const float* __restrict__ tok_emb, const float* __restrict__ act_emb,
    const float* __restrict__ lvl_emb, float* __restrict__ x) {
  int row = blockIdx.x;
  int b = row / SEQ, s = row % SEQ;
  const float* src;
  if (s < CTXEND) {
    int i = s / 37, r = s % 37;
    if (r < 36) src = tok_emb + (size_t)ft[(b * 5 + i) * TPF + r] * DM;
    else        src = act_emb + (size_t)act[b * KFRM + i] * DM;
  } else {
    src = tok_emb + (size_t)ft[(b * 5 + 4) * TPF + (s - CTXEND)] * DM;
  }
  const float* le = lvl_emb + (size_t)lvl[b] * DM;
  float* dst = x + (size_t)row * DM;
  for (int d = threadIdx.x; d < DM; d += 256) dst[d] = src[d] + le[d];
}

// ---------------- LayerNorm (f32 in -> bf16 out), one wave per row ----------------
__global__ __launch_bounds__(256) void ln_rows(const float* __restrict__ x,
    const float* __restrict__ g, const float* __restrict__ bb,
    u16* __restrict__ out, int nrows) {
  int wid = blockIdx.x * 4 + (threadIdx.x >> 6);
  if (wid >= nrows) return;
  int lane = threadIdx.x & 63;
  const float* row = x + (size_t)wid * DM;
  float s = 0.f, ss = 0.f;
  float v[16];
#pragma unroll
  for (int i = 0; i < 16; i++) {
    v[i] = row[i * 64 + lane];
    s += v[i]; ss += v[i] * v[i];
  }
#pragma unroll
  for (int m = 32; m; m >>= 1) { s += __shfl_xor(s, m, 64); ss += __shfl_xor(ss, m, 64); }
  float mean = s * (1.f / DM);
  float var = ss * (1.f / DM) - mean * mean;
  float rstd = rsqrtf(var + 1e-5f);
  u16* dst = out + (size_t)wid * DM;
#pragma unroll
  for (int i = 0; i < 16; i++) {
    int d = i * 64 + lane;
    dst[d] = f2b((v[i] - mean) * rstd * g[d] + bb[d]);
  }
}

// ---------------- final LN: gather predict rows (bf16) + row 183 (f32) ----------------
__global__ __launch_bounds__(256) void lnf_kernel(const float* __restrict__ x,
    const float* __restrict__ g, const float* __restrict__ bb,
    u16* __restrict__ pred, float* __restrict__ r183) {
  int wid = blockIdx.x * 4 + (threadIdx.x >> 6);
  if (wid >= BATCH * 37) return;
  int lane = threadIdx.x & 63;
  int b = wid / 37, si = wid % 37, s = 147 + si;
  const float* row = x + ((size_t)b * SEQ + s) * DM;
  float sum = 0.f, ss = 0.f;
  float v[16];
#pragma unroll
  for (int i = 0; i < 16; i++) {
    v[i] = row[i * 64 + lane];
    sum += v[i]; ss += v[i] * v[i];
  }
#pragma unroll
  for (int m = 32; m; m >>= 1) { sum += __shfl_xor(sum, m, 64); ss += __shfl_xor(ss, m, 64); }
  float mean = sum * (1.f / DM);
  float var = ss * (1.f / DM) - mean * mean;
  float rstd = rsqrtf(var + 1e-5f);
  if (s < 183) {
    u16* dst = pred + ((size_t)b * 36 + si) * DM;
#pragma unroll
    for (int i = 0; i < 16; i++) {
      int d = i * 64 + lane;
      dst[d] = f2b((v[i] - mean) * rstd * g[d] + bb[d]);
    }
  } else {
    float* dst = r183 + (size_t)b * DM;
#pragma unroll
    for (int i = 0; i < 16; i++) {
      int d = i * 64 + lane;
      dst[d] = (v[i] - mean) * rstd * g[d] + bb[d];
    }
  }
}

// ---------------- 128x128 bf16 NT GEMM (BK=32, 4 waves, dbuf 32KB LDS, 4 blocks/CU) ----
// C[n,m] = sum_k A[n,k]*W[m,k]
// m97 regime: small blocks, 4 independent blocks/CU (launch_bounds(256,4)); cross-block
// async overlap hides the stage->barrier drain. Wave (wm,wn) owns a 64x64 sub-tile,
// acc = 4x4 f32x4 = 64 AGPR.
// LDS rows are 64B; swizzle o ^= (((o>>6)&3 ^ (o>>8)&3))<<4 -> frag-read lanes land
// exactly 2 per bank-quad (free), involution, staging-compatible (rule #21).
// MODE 0: bf16 out = acc + bias | 1: f32 += acc+bias | 2: bf16 gelu(acc+bias) | 3: f32 = acc
__device__ inline void gld_lds16(const void* g, void* l) {
  __builtin_amdgcn_global_load_lds((const __attribute__((address_space(1))) void*)g,
                                   (__attribute__((address_space(3))) void*)l, 16, 0, 0);
}

__device__ inline int swz64(int o) {
  return o ^ (((((o >> 6) & 3) ^ ((o >> 8) & 3))) << 4);
}

template <int MODE>
__global__ __launch_bounds__(256, 4) void gemm97(
    const u16* __restrict__ A, const u16* __restrict__ W,
    const float* __restrict__ bias, float* __restrict__ Cf, u16* __restrict__ Cb,
    int M, int Kdim) {
  __shared__ alignas(16) char As[2][8192];
  __shared__ alignas(16) char Bs[2][8192];
  const int tid = threadIdx.x;
  const int wave = tid >> 6, lane = tid & 63;
  const int wm = wave >> 1, wn = wave & 1;
  const int lr = lane & 15, g = lane >> 4;

  // XCD-chunked block swizzle (all grids here have nwg % 8 == 0)
  const int nbx = gridDim.x;
  int nwg = gridDim.x * gridDim.y;
  int id = blockIdx.y * gridDim.x + blockIdx.x;
  int id2 = (id & 7) * (nwg >> 3) + (id >> 3);
  const int row0 = (id2 / nbx) * 128, col0 = (id2 % nbx) * 128;

  const size_t krow = (size_t)Kdim * 2;  // bytes per logical row
  const char* Abase = (const char*)A + (size_t)row0 * krow;
  const char* Wbase = (const char*)W + (size_t)col0 * krow;

  auto stage = [&](int t, int buf) {
    const char* Ab = Abase + (size_t)t * 64;
    const char* Wb = Wbase + (size_t)t * 64;
#pragma unroll
    for (int c = 0; c < 2; c++) {
      int ob = wave * 2048 + c * 1024;      // wave-uniform LDS base (linear dest)
      int o = ob + lane * 16;               // this lane's implicit dest
      int os = swz64(o);                    // inverse-swizzled logical source
      gld_lds16(Ab + (size_t)(os >> 6) * krow + (os & 63), &As[buf][ob]);
      gld_lds16(Wb + (size_t)(os >> 6) * krow + (os & 63), &Bs[buf][ob]);
    }
  };

  const int NT = Kdim >> 5;   // K-tiles of 32
  f32x4 acc[4][4] = {};

  stage(0, 0);
  __syncthreads();

#pragma unroll 1
  for (int t = 0; t < NT; t++) {
    int p = t & 1;
    if (t + 1 < NT) stage(t + 1, p ^ 1);
    bf16x8 af[4], bfj[4];
#pragma unroll
    for (int i = 0; i < 4; i++) {
      int r = wm * 64 + i * 16 + lr;
      int o = r * 64 + g * 16;
      af[i] = *(const bf16x8*)(As[p] + swz64(o));
    }
#pragma unroll
    for (int j = 0; j < 4; j++) {
      int r = wn * 64 + j * 16 + lr;
      int o = r * 64 + g * 16;
      bfj[j] = *(const bf16x8*)(Bs[p] + swz64(o));
    }
#pragma unroll
    for (int i = 0; i < 4; i++)
#pragma unroll
      for (int j = 0; j < 4; j++)
        acc[i][j] = __builtin_amdgcn_mfma_f32_16x16x32_bf16(af[i], bfj[j], acc[i][j], 0, 0, 0);
    __syncthreads();
  }

  // epilogue
  float bj[4];
  if (MODE != 3) {
#pragma unroll
    for (int j = 0; j < 4; j++) bj[j] = bias[col0 + wn * 64 + j * 16 + lr];
  }
#pragma unroll
  for (int i = 0; i < 4; i++) {
#pragma unroll
    for (int j = 0; j < 4; j++) {
#pragma unroll
      for (int r = 0; r < 4; r++) {
        int grow = row0 + wm * 64 + i * 16 + g * 4 + r;
        int gcol = col0 + wn * 64 + j * 16 + lr;
        float v = acc[i][j][r];
        size_t idx = (size_t)grow * M + gcol;
        if (MODE == 0) { v += bj[j]; Cb[idx] = f2b(v); }
        else if (MODE == 1) { v += bj[j]; Cf[idx] += v; }
        else if (MODE == 2) {
          v += bj[j];
          // tanh-form GELU: x*sigmoid(1.5957692*(x+0.044715x^3)), |err|<~7e-4
          float z = 1.5957692f * (v + 0.044715f * v * v * v);
          v = v / (1.f + __expf(-z));
          Cb[idx] = f2b(v);
        } else {
          Cf[idx] = v;
        }
      }
    }
  }
}

// ---------------- MFMA attention ----------------
#define SP 192
#define KST 72
#define VST 200
#define PST 200

__device__ inline int block_of(int s) {
  return (s < CTXEND) ? (2 * (s / 37) + ((s % 37) == 36)) : 8;
}

__global__ __launch_bounds__(256) void attn_mfma(const u16* __restrict__ qkv,
    u16* __restrict__ outb, const float* __restrict__ rc, const float* __restrict__ rs) {
  __shared__ alignas(16) u16 Ks[SP][KST];
  __shared__ alignas(16) u16 Vt[HD][VST];
  __shared__ alignas(16) u16 Ps[4][16][PST];
  const int b = blockIdx.x >> 4, h = blockIdx.x & 15;
  const int tid = threadIdx.x, wave = tid >> 6, lane = tid & 63;
  const int lr = lane & 15, g = lane >> 4, g4 = g * 4;
  const u16* base = qkv + (size_t)b * SEQ * 3072 + h * HD;

  for (int idx = tid; idx < SP * 32; idx += 256) {
    int s = idx >> 5, d = idx & 31;
    if (s < SEQ) {
      const u16* kr = base + (size_t)s * 3072 + 1024;
      float x1 = b2f(kr[d]), x2 = b2f(kr[d + 32]);
      float c = rc[s * 32 + d], sn = rs[s * 32 + d];
      Ks[s][d] = f2b(x1 * c - x2 * sn);
      Ks[s][d + 32] = f2b(x1 * sn + x2 * c);
    } else {
      Ks[s][d] = 0;
      Ks[s][d + 32] = 0;
    }
  }
  for (int idx = tid; idx < SP * HD; idx += 256) {
    int k = idx >> 6, d = idx & 63;
    Vt[d][k] = (k < SEQ) ? base[(size_t)k * 3072 + 2048 + d] : (u16)0;
  }
  __syncthreads();

#pragma unroll 1
  for (int t = 0; t < 3; t++) {
    const int q0 = (wave + 4 * t) * 16;
    const int q_lane = q0 + lr;
    const int qc = (q_lane < SEQ) ? q_lane : (SEQ - 1);

    U16x8 raw0 = *(const U16x8*)(base + (size_t)qc * 3072 + g * 8);
    U16x8 raw1 = *(const U16x8*)(base + (size_t)qc * 3072 + 32 + g * 8);
    bf16x8 qa0, qa1;
#pragma unroll
    for (int i = 0; i < 8; i++) {
      float x1 = b2f(raw0.v[i]), x2 = b2f(raw1.v[i]);
      int di = g * 8 + i;
      float c = rc[qc * 32 + di], sn = rs[qc * 32 + di];
      qa0[i] = (__bf16)(x1 * c - x2 * sn);
      qa1[i] = (__bf16)(x1 * sn + x2 * c);
    }

    f32x4 accs[12];
#pragma unroll
    for (int kt = 0; kt < 12; kt++) accs[kt] = (f32x4){0.f, 0.f, 0.f, 0.f};
#pragma unroll
    for (int kt = 0; kt < 12; kt++) {
      bf16x8 kb0 = *(const bf16x8*)&Ks[kt * 16 + lr][g * 8];
      bf16x8 kb1 = *(const bf16x8*)&Ks[kt * 16 + lr][32 + g * 8];
      accs[kt] = __builtin_amdgcn_mfma_f32_16x16x32_bf16(qa0, kb0, accs[kt], 0, 0, 0);
      accs[kt] = __builtin_amdgcn_mfma_f32_16x16x32_bf16(qa1, kb1, accs[kt], 0, 0, 0);
    }

    int qb[4];
#pragma unroll
    for (int r = 0; r < 4; r++) qb[r] = block_of(q0 + g4 + r);
    float mr[4] = {-3e38f, -3e38f, -3e38f, -3e38f};
#pragma unroll
    for (int kt = 0; kt < 12; kt++) {
      int k = kt * 16 + lr;
      bool kv = k < SEQ;
      int kb = kv ? block_of(k) : 9;
#pragma unroll
      for (int r = 0; r < 4; r++) {
        int q = q0 + g4 + r;
        bool ok = kv && (kb <= qb[r]) && !(q >= CTXEND && k >= CTXEND && k > q);
        float s = ok ? accs[kt][r] * 0.125f : -3e38f;
        accs[kt][r] = s;
        mr[r] = fmaxf(mr[r], s);
      }
    }
#pragma unroll
    for (int m = 1; m <= 8; m <<= 1)
#pragma unroll
      for (int r = 0; r < 4; r++) mr[r] = fmaxf(mr[r], __shfl_xor(mr[r], m, 64));

    float sr[4] = {0.f, 0.f, 0.f, 0.f};
#pragma unroll
    for (int kt = 0; kt < 12; kt++) {
#pragma unroll
      for (int r = 0; r < 4; r++) {
        float e = (accs[kt][r] > -1e37f) ? __expf(accs[kt][r] - mr[r]) : 0.f;
        Ps[wave][g4 + r][kt * 16 + lr] = f2b(e);
        sr[r] += e;
      }
    }
#pragma unroll
    for (int m = 1; m <= 8; m <<= 1)
#pragma unroll
      for (int r = 0; r < 4; r++) sr[r] += __shfl_xor(sr[r], m, 64);
    float inv[4];
#pragma unroll
    for (int r = 0; r < 4; r++) inv[r] = 1.f / sr[r];

    __builtin_amdgcn_s_waitcnt(0);

    f32x4 acco[4];
#pragma unroll
    for (int dt = 0; dt < 4; dt++) acco[dt] = (f32x4){0.f, 0.f, 0.f, 0.f};
#pragma unroll
    for (int kc = 0; kc < 6; kc++) {
      bf16x8 pa = *(const bf16x8*)&Ps[wave][lr][kc * 32 + g * 8];
#pragma unroll
      for (int dt = 0; dt < 4; dt++) {
        bf16x8 vb = *(const bf16x8*)&Vt[dt * 16 + lr][kc * 32 + g * 8];
        acco[dt] = __builtin_amdgcn_mfma_f32_16x16x32_bf16(pa, vb, acco[dt], 0, 0, 0);
      }
    }

#pragma unroll
    for (int dt = 0; dt < 4; dt++) {
#pragma unroll
      for (int r = 0; r < 4; r++) {
        int q = q0 + g4 + r;
        if (q < SEQ)
          outb[((size_t)b * SEQ + q) * DM + h * HD + dt * 16 + lr] = f2b(acco[dt][r] * inv[r]);
      }
    }
  }
}

// ---------------- death logit ----------------
__global__ void death_kernel(const float* __restrict__ r183, const float* __restrict__ dw,
                             const float* __restrict__ db, float* __restrict__ out) {
  int b = blockIdx.x, lane = threadIdx.x;
  float a = 0.f;
  for (int d = lane; d < DM; d += 64) a += r183[(size_t)b * DM + d] * dw[d];
#pragma unroll
  for (int m = 32; m; m >>= 1) a += __shfl_xor(a, m, 64);
  if (lane == 0) out[(size_t)BATCH * TPF * VOCAB + b] = a + db[0];
}

extern "C" void kernel_launch(void* const* d_in, const int* in_sizes, int n_in,
                              void* d_out, int out_size, void* d_ws, size_t ws_size,
                              hipStream_t stream) {
  const int* ft = (const int*)d_in[0];
  const int* act = (const int*)d_in[1];
  const int* lvl = (const int*)d_in[2];
  const float* tok_emb = (const float*)d_in[3];
  const float* act_emb = (const float*)d_in[4];
  const float* lvl_emb = (const float*)d_in[5];
  const float* ln1_g = (const float*)d_in[6];
  const float* ln1_b = (const float*)d_in[7];
  const float* qkv_w = (const float*)d_in[8];
  const float* qkv_b = (const float*)d_in[9];
  const float* out_w = (const float*)d_in[10];
  const float* out_b = (const float*)d_in[11];
  const float* ln2_g = (const float*)d_in[12];
  const float* ln2_b = (const float*)d_in[13];
  const float* mlp_w1 = (const float*)d_in[14];
  const float* mlp_b1 = (const float*)d_in[15];
  const float* mlp_w2 = (const float*)d_in[16];
  const float* mlp_b2 = (const float*)d_in[17];
  const float* lnf_g = (const float*)d_in[18];
  const float* lnf_b = (const float*)d_in[19];
  const float* head_w = (const float*)d_in[20];
  const float* death_w = (const float*)d_in[21];
  const float* death_b = (const float*)d_in[22];
  const float* rope_cos = (const float*)d_in[23];
  const float* rope_sin = (const float*)d_in[24];

  char* ws = (char*)d_ws;
  size_t off = 0;
  auto alloc = [&](size_t bytes) {
    void* p = ws + off;
    off += (bytes + 255) & ~(size_t)255;
    return p;
  };
  float* x   = (float*)alloc((size_t)NTOK * DM * 4);
  u16* hb    = (u16*)alloc((size_t)NTOK * DM * 2);
  u16* big   = (u16*)alloc((size_t)NTOK * 4096 * 2);
  u16* wq    = (u16*)alloc((size_t)3072 * 1024 * 2);
  u16* wo    = (u16*)alloc((size_t)1024 * 1024 * 2);
  u16* w1    = (u16*)alloc((size_t)4096 * 1024 * 2);
  u16* w2    = (u16*)alloc((size_t)4096 * 1024 * 2);
  u16* pred  = (u16*)alloc((size_t)BATCH * 36 * DM * 2);
  float* r183 = (float*)alloc((size_t)BATCH * DM * 4);

  float* out = (float*)d_out;

  embed_kernel<<<NTOK, 256, 0, stream>>>(ft, act, lvl, tok_emb, act_emb, lvl_emb, x);

  for (int l = 0; l < NLAYER; l++) {
    conv_layer<<<(CN1 + CN2 + 2 * CN3) / 256, 256, 0, stream>>>(
        (const float4*)(qkv_w + (size_t)l * 3072 * 1024), (U16x4*)wq,
        (const float4*)(out_w + (size_t)l * 1024 * 1024), (U16x4*)wo,
        (const float4*)(mlp_w1 + (size_t)l * 4096 * 1024), (U16x4*)w1,
        (const float4*)(mlp_w2 + (size_t)l * 4096 * 1024), (U16x4*)w2);

    ln_rows<<<NTOK / 4, 256, 0, stream>>>(x, ln1_g + l * DM, ln1_b + l * DM, hb, NTOK);
    gemm97<0><<<dim3(3072 / 128, NTOK / 128), 256, 0, stream>>>(
        hb, wq, qkv_b + (size_t)l * 3072, nullptr, big, 3072, 1024);
    attn_mfma<<<BATCH * NH, 256, 0, stream>>>(big, hb, rope_cos, rope_sin);
    gemm97<1><<<dim3(1024 / 128, NTOK / 128), 256, 0, stream>>>(
        hb, wo, out_b + (size_t)l * DM, x, nullptr, 1024, 1024);
    ln_rows<<<NTOK / 4, 256, 0, stream>>>(x, ln2_g + l * DM, ln2_b + l * DM, hb, NTOK);
    gemm97<2><<<dim3(4096 / 128, NTOK / 128), 256, 0, stream>>>(
        hb, w1, mlp_b1 + (size_t)l * 4096, nullptr, big, 4096, 1024);
    gemm97<1><<<dim3(1024 / 128, NTOK / 128), 256, 0, stream>>>(
        big, w2, mlp_b2 + (size_t)l * DM, x, nullptr, 1024, 4096);
  }

  lnf_kernel<<<BATCH * 37 / 4, 256, 0, stream>>>(x, lnf_g, lnf_b, pred, r183);
  conv_bf16<<<4096 * 1024 / 4 / 256, 256, 0, stream>>>(
      (const float4*)head_w, (U16x4*)w1, 4096 * 1024 / 4);
  gemm97<3><<<dim3(4096 / 128, BATCH * 36 / 128), 256, 0, stream>>>(
      pred, w1, nullptr, out, nullptr, 4096, 1024);
  death_kernel<<<BATCH, 64, 0, stream>>>(r183, death_w, death_b, out);
}

// Round 12
// 3874.385 us; speedup vs baseline: 1.0775x; 1.0759x over previous
//
#include <hip/hip_runtime.h>
#include <math.h>

#define TPF 36
#define KFRM 4
#define DM 1024
#define NH 16
#define HD 64
#define NLAYER 8
#define VOCAB 4096
#define SEQ 184
#define BATCH 64
#define NTOK (BATCH * SEQ)   // 11776
#define CTXEND 148

typedef unsigned short u16;
typedef unsigned int u32;
typedef __bf16 bf16x8 __attribute__((ext_vector_type(8)));
typedef float f32x4 __attribute__((ext_vector_type(4)));

struct alignas(8) U16x4 { u16 x, y, z, w; };
struct alignas(16) U16x8 { u16 v[8]; };

__device__ inline u16 f2b(float f) {
  u32 u = __float_as_uint(f);
  u += 0x7FFFu + ((u >> 16) & 1u);
  return (u16)(u >> 16);
}
__device__ inline float b2f(u16 h) { return __uint_as_float(((u32)h) << 16); }

// ---------------- f32 -> bf16 conversion ----------------
__global__ __launch_bounds__(256) void conv_bf16(const float4* __restrict__ in,
                                                 U16x4* __restrict__ out, int n4) {
  int i = blockIdx.x * 256 + threadIdx.x;
  if (i >= n4) return;
  float4 v = in[i];
  U16x4 o;
  o.x = f2b(v.x); o.y = f2b(v.y); o.z = f2b(v.z); o.w = f2b(v.w);
  out[i] = o;
}

// fused per-layer conversion: qkv_w + out_w + mlp_w1 + mlp_w2 in one dispatch
#define CN1 (3072 * 1024 / 4)
#define CN2 (1024 * 1024 / 4)
#define CN3 (4096 * 1024 / 4)
__global__ __launch_bounds__(256) void conv_layer(
    const float4* __restrict__ s1, U16x4* __restrict__ d1,
    const float4* __restrict__ s2, U16x4* __restrict__ d2,
    const float4* __restrict__ s3, U16x4* __restrict__ d3,
    const float4* __restrict__ s4, U16x4* __restrict__ d4) {
  int j = blockIdx.x * 256 + threadIdx.x;
  const float4* s; U16x4* d;
  if (j < CN1) { s = s1; d = d1; }
  else if ((j -= CN1) < CN2) { s = s2; d = d2; }
  else if ((j -= CN2) < CN3) { s = s3; d = d3; }
  else { j -= CN3; s = s4; d = d4; }
  float4 v = s[j];
  U16x4 o;
  o.x = f2b(v.x); o.y = f2b(v.y); o.z = f2b(v.z); o.w = f2b(v.w);
  d[j] = o;
}

// ---------------- embedding ----------------
__global__ __launch_bounds__(256) void embed_kernel(
    const int* __restrict__ ft, const int* __restrict__ act, const int* __restrict__ lvl,
    const float* __restrict__ tok_emb, const float* __restrict__ act_emb,
    const float* __restrict__ lvl_emb, float* __restrict__ x) {
  int row = blockIdx.x;
  int b = row / SEQ, s = row % SEQ;
  const float* src;
  if (s < CTXEND) {
    int i = s / 37, r = s % 37;
    if (r < 36) src = tok_emb + (size_t)ft[(b * 5 + i) * TPF + r] * DM;
    else        src = act_emb + (size_t)act[b * KFRM + i] * DM;
  } else {
    src = tok_emb + (size_t)ft[(b * 5 + 4) * TPF + (s - CTXEND)] * DM;
  }
  const float* le = lvl_emb + (size_t)lvl[b] * DM;
  float* dst = x + (size_t)row * DM;
  for (int d = threadIdx.x; d < DM; d += 256) dst[d] = src[d] + le[d];
}

// ---------------- LayerNorm (f32 in -> bf16 out), one wave per row ----------------
__global__ __launch_bounds__(256) void ln_rows(const float* __restrict__ x,
    const float* __restrict__ g, const float* __restrict__ bb,
    u16* __restrict__ out, int nrows) {
  int wid = blockIdx.x * 4 + (threadIdx.x >> 6);
  if (wid >= nrows) return;
  int lane = threadIdx.x & 63;
  const float* row = x + (size_t)wid * DM;
  float s = 0.f, ss = 0.f;
  float v[16];
#pragma unroll
  for (int i = 0; i < 16; i++) {
    v[i] = row[i * 64 + lane];
    s += v[i]; ss += v[i] * v[i];
  }
#pragma unroll
  for (int m = 32; m; m >>= 1) { s += __shfl_xor(s, m, 64); ss += __shfl_xor(ss, m, 64); }
  float mean = s * (1.f / DM);
  float var = ss * (1.f / DM) - mean * mean;
  float rstd = rsqrtf(var + 1e-5f);
  u16* dst = out + (size_t)wid * DM;
#pragma unroll
  for (int i = 0; i < 16; i++) {
    int d = i * 64 + lane;
    dst[d] = f2b((v[i] - mean) * rstd * g[d] + bb[d]);
  }
}

// ---------------- final LN: gather predict rows (bf16) + row 183 (f32) ----------------
__global__ __launch_bounds__(256) void lnf_kernel(const float* __restrict__ x,
    const float* __restrict__ g, const float* __restrict__ bb,
    u16* __restrict__ pred, float* __restrict__ r183) {
  int wid = blockIdx.x * 4 + (threadIdx.x >> 6);
  if (wid >= BATCH * 37) return;
  int lane = threadIdx.x & 63;
  int b = wid / 37, si = wid % 37, s = 147 + si;
  const float* row = x + ((size_t)b * SEQ + s) * DM;
  float sum = 0.f, ss = 0.f;
  float v[16];
#pragma unroll
  for (int i = 0; i < 16; i++) {
    v[i] = row[i * 64 + lane];
    sum += v[i]; ss += v[i] * v[i];
  }
#pragma unroll
  for (int m = 32; m; m >>= 1) { sum += __shfl_xor(sum, m, 64); ss += __shfl_xor(ss, m, 64); }
  float mean = sum * (1.f / DM);
  float var = ss * (1.f / DM) - mean * mean;
  float rstd = rsqrtf(var + 1e-5f);
  if (s < 183) {
    u16* dst = pred + ((size_t)b * 36 + si) * DM;
#pragma unroll
    for (int i = 0; i < 16; i++) {
      int d = i * 64 + lane;
      dst[d] = f2b((v[i] - mean) * rstd * g[d] + bb[d]);
    }
  } else {
    float* dst = r183 + (size_t)b * DM;
#pragma unroll
    for (int i = 0; i < 16; i++) {
      int d = i * 64 + lane;
      dst[d] = (v[i] - mean) * rstd * g[d] + bb[d];
    }
  }
}

// ---------------- 256x256 bf16 NT GEMM (BK=64, 16 waves, dbuf LDS, swizzled) ----------
// Round-9 champion: 137 us mlp1, MfmaUtil 31%, 0 conflicts.
__device__ inline void gld_lds16(const void* g, void* l) {
  __builtin_amdgcn_global_load_lds((const __attribute__((address_space(1))) void*)g,
                                   (__attribute__((address_space(3))) void*)l, 16, 0, 0);
}

template <int MODE>
__global__ __launch_bounds__(1024) void gemm16(
    const u16* __restrict__ A, const u16* __restrict__ W,
    const float* __restrict__ bias, float* __restrict__ Cf, u16* __restrict__ Cb,
    int M, int Kdim) {
  __shared__ alignas(16) char As[2][32768];
  __shared__ alignas(16) char Bs[2][32768];
  const int tid = threadIdx.x;
  const int wave = tid >> 6, lane = tid & 63;
  const int wm = wave >> 2, wn = wave & 3;
  const int lr = lane & 15, g = lane >> 4;

  const int nbx = gridDim.x;
  int nwg = gridDim.x * gridDim.y;
  int id = blockIdx.y * gridDim.x + blockIdx.x;
  int id2 = (id & 7) * (nwg >> 3) + (id >> 3);
  const int row0 = (id2 / nbx) * 256, col0 = (id2 % nbx) * 256;

  const size_t krow = (size_t)Kdim * 2;
  const char* Abase = (const char*)A + (size_t)row0 * krow;
  const char* Wbase = (const char*)W + (size_t)col0 * krow;

  auto stage = [&](int t, int buf) {
    const char* Ab = Abase + (size_t)t * 128;
    const char* Wb = Wbase + (size_t)t * 128;
#pragma unroll
    for (int c = 0; c < 2; c++) {
      int ob = wave * 2048 + c * 1024;
      int o = ob + lane * 16;
      int os = o ^ (((o >> 7) & 7) << 4);
      gld_lds16(Ab + (size_t)(os >> 7) * krow + (os & 127), &As[buf][ob]);
      gld_lds16(Wb + (size_t)(os >> 7) * krow + (os & 127), &Bs[buf][ob]);
    }
  };

  const int NT = Kdim >> 6;
  f32x4 acc[4][4] = {};

  stage(0, 0);
  __syncthreads();

#pragma unroll 1
  for (int t = 0; t < NT; t++) {
    int p = t & 1;
    if (t + 1 < NT) stage(t + 1, p ^ 1);
#pragma unroll
    for (int kk = 0; kk < 2; kk++) {
      bf16x8 af[4], bfj[4];
#pragma unroll
      for (int i = 0; i < 4; i++) {
        int r = wm * 64 + i * 16 + lr;
        int o = r * 128 + kk * 64 + g * 16;
        af[i] = *(const bf16x8*)(As[p] + (o ^ ((r & 7) << 4)));
      }
#pragma unroll
      for (int j = 0; j < 4; j++) {
        int r = wn * 64 + j * 16 + lr;
        int o = r * 128 + kk * 64 + g * 16;
        bfj[j] = *(const bf16x8*)(Bs[p] + (o ^ ((r & 7) << 4)));
      }
#pragma unroll
      for (int i = 0; i < 4; i++)
#pragma unroll
        for (int j = 0; j < 4; j++)
          acc[i][j] = __builtin_amdgcn_mfma_f32_16x16x32_bf16(af[i], bfj[j], acc[i][j], 0, 0, 0);
    }
    __syncthreads();
  }

  float bj[4];
  if (MODE != 3) {
#pragma unroll
    for (int j = 0; j < 4; j++) bj[j] = bias[col0 + wn * 64 + j * 16 + lr];
  }
#pragma unroll
  for (int i = 0; i < 4; i++) {
#pragma unroll
    for (int j = 0; j < 4; j++) {
#pragma unroll
      for (int r = 0; r < 4; r++) {
        int grow = row0 + wm * 64 + i * 16 + g * 4 + r;
        int gcol = col0 + wn * 64 + j * 16 + lr;
        float v = acc[i][j][r];
        size_t idx = (size_t)grow * M + gcol;
        if (MODE == 0) { v += bj[j]; Cb[idx] = f2b(v); }
        else if (MODE == 1) { v += bj[j]; Cf[idx] += v; }
        else if (MODE == 2) {
          v += bj[j];
          float z = 1.5957692f * (v + 0.044715f * v * v * v);
          v = v / (1.f + __expf(-z));
          Cb[idx] = f2b(v);
        } else {
          Cf[idx] = v;
        }
      }
    }
  }
}

// ---------------- MFMA attention (conflict-fixed LDS layouts) ----------------
// Ks: flat [192 rows][128 B], XOR-swizzled with the PROVEN o^((row&7)<<4) (0-conflict
// in gemm16's identical read geometry). Vt/Ps: stride 216 u16 (432 B = 108 dw == 12
// mod 32 -> 2-way bank aliasing = free per m136). LDS total 79872 B -> 2 blocks/CU.
#define SP 192
#define VST 216
#define PST 216

__device__ inline int block_of(int s) {
  return (s < CTXEND) ? (2 * (s / 37) + ((s % 37) == 36)) : 8;
}

__global__ __launch_bounds__(256) void attn_mfma(const u16* __restrict__ qkv,
    u16* __restrict__ outb, const float* __restrict__ rc, const float* __restrict__ rs) {
  __shared__ alignas(16) char KsB[SP * 128];
  __shared__ alignas(16) u16 Vt[HD][VST];
  __shared__ alignas(16) u16 Ps[4][16][PST];
  const int b = blockIdx.x >> 4, h = blockIdx.x & 15;
  const int tid = threadIdx.x, wave = tid >> 6, lane = tid & 63;
  const int lr = lane & 15, g = lane >> 4, g4 = g * 4;
  const u16* base = qkv + (size_t)b * SEQ * 3072 + h * HD;

  // stage rope'd K into swizzled [192][128B] layout (zero padded rows)
  for (int idx = tid; idx < SP * 32; idx += 256) {
    int s = idx >> 5, d = idx & 31;
    int o0 = s * 128 + d * 2;
    int o1 = s * 128 + 64 + d * 2;
    u16 v0 = 0, v1 = 0;
    if (s < SEQ) {
      const u16* kr = base + (size_t)s * 3072 + 1024;
      float x1 = b2f(kr[d]), x2 = b2f(kr[d + 32]);
      float c = rc[s * 32 + d], sn = rs[s * 32 + d];
      v0 = f2b(x1 * c - x2 * sn);
      v1 = f2b(x1 * sn + x2 * c);
    }
    *(u16*)(KsB + (o0 ^ ((s & 7) << 4))) = v0;
    *(u16*)(KsB + (o1 ^ ((s & 7) << 4))) = v1;
  }
  // stage V transposed (zero-fill padded cols)
  for (int idx = tid; idx < SP * HD; idx += 256) {
    int k = idx >> 6, d = idx & 63;
    Vt[d][k] = (k < SEQ) ? base[(size_t)k * 3072 + 2048 + d] : (u16)0;
  }
  __syncthreads();

#pragma unroll 1
  for (int t = 0; t < 3; t++) {
    const int q0 = (wave + 4 * t) * 16;
    const int q_lane = q0 + lr;
    const int qc = (q_lane < SEQ) ? q_lane : (SEQ - 1);

    U16x8 raw0 = *(const U16x8*)(base + (size_t)qc * 3072 + g * 8);
    U16x8 raw1 = *(const U16x8*)(base + (size_t)qc * 3072 + 32 + g * 8);
    bf16x8 qa0, qa1;
#pragma unroll
    for (int i = 0; i < 8; i++) {
      float x1 = b2f(raw0.v[i]), x2 = b2f(raw1.v[i]);
      int di = g * 8 + i;
      float c = rc[qc * 32 + di], sn = rs[qc * 32 + di];
      qa0[i] = (__bf16)(x1 * c - x2 * sn);
      qa1[i] = (__bf16)(x1 * sn + x2 * c);
    }

    f32x4 accs[12];
#pragma unroll
    for (int kt = 0; kt < 12; kt++) accs[kt] = (f32x4){0.f, 0.f, 0.f, 0.f};
#pragma unroll
    for (int kt = 0; kt < 12; kt++) {
      int rt = kt * 16 + lr;
      bf16x8 kb0 = *(const bf16x8*)(KsB + ((rt * 128 + g * 16) ^ ((rt & 7) << 4)));
      bf16x8 kb1 = *(const bf16x8*)(KsB + ((rt * 128 + 64 + g * 16) ^ ((rt & 7) << 4)));
      accs[kt] = __builtin_amdgcn_mfma_f32_16x16x32_bf16(qa0, kb0, accs[kt], 0, 0, 0);
      accs[kt] = __builtin_amdgcn_mfma_f32_16x16x32_bf16(qa1, kb1, accs[kt], 0, 0, 0);
    }

    int qb[4];
#pragma unroll
    for (int r = 0; r < 4; r++) qb[r] = block_of(q0 + g4 + r);
    float mr[4] = {-3e38f, -3e38f, -3e38f, -3e38f};
#pragma unroll
    for (int kt = 0; kt < 12; kt++) {
      int k = kt * 16 + lr;
      bool kv = k < SEQ;
      int kb = kv ? block_of(k) : 9;
#pragma unroll
      for (int r = 0; r < 4; r++) {
        int q = q0 + g4 + r;
        bool ok = kv && (kb <= qb[r]) && !(q >= CTXEND && k >= CTXEND && k > q);
        float s = ok ? accs[kt][r] * 0.125f : -3e38f;
        accs[kt][r] = s;
        mr[r] = fmaxf(mr[r], s);
      }
    }
#pragma unroll
    for (int m = 1; m <= 8; m <<= 1)
#pragma unroll
      for (int r = 0; r < 4; r++) mr[r] = fmaxf(mr[r], __shfl_xor(mr[r], m, 64));

    float sr[4] = {0.f, 0.f, 0.f, 0.f};
#pragma unroll
    for (int kt = 0; kt < 12; kt++) {
#pragma unroll
      for (int r = 0; r < 4; r++) {
        float e = (accs[kt][r] > -1e37f) ? __expf(accs[kt][r] - mr[r]) : 0.f;
        Ps[wave][g4 + r][kt * 16 + lr] = f2b(e);
        sr[r] += e;
      }
    }
#pragma unroll
    for (int m = 1; m <= 8; m <<= 1)
#pragma unroll
      for (int r = 0; r < 4; r++) sr[r] += __shfl_xor(sr[r], m, 64);
    float inv[4];
#pragma unroll
    for (int r = 0; r < 4; r++) inv[r] = 1.f / sr[r];

    __builtin_amdgcn_s_waitcnt(0);

    f32x4 acco[4];
#pragma unroll
    for (int dt = 0; dt < 4; dt++) acco[dt] = (f32x4){0.f, 0.f, 0.f, 0.f};
#pragma unroll
    for (int kc = 0; kc < 6; kc++) {
      bf16x8 pa = *(const bf16x8*)&Ps[wave][lr][kc * 32 + g * 8];
#pragma unroll
      for (int dt = 0; dt < 4; dt++) {
        bf16x8 vb = *(const bf16x8*)&Vt[dt * 16 + lr][kc * 32 + g * 8];
        acco[dt] = __builtin_amdgcn_mfma_f32_16x16x32_bf16(pa, vb, acco[dt], 0, 0, 0);
      }
    }

#pragma unroll
    for (int dt = 0; dt < 4; dt++) {
#pragma unroll
      for (int r = 0; r < 4; r++) {
        int q = q0 + g4 + r;
        if (q < SEQ)
          outb[((size_t)b * SEQ + q) * DM + h * HD + dt * 16 + lr] = f2b(acco[dt][r] * inv[r]);
      }
    }
  }
}

// ---------------- death logit ----------------
__global__ void death_kernel(const float* __restrict__ r183, const float* __restrict__ dw,
                             const float* __restrict__ db, float* __restrict__ out) {
  int b = blockIdx.x, lane = threadIdx.x;
  float a = 0.f;
  for (int d = lane; d < DM; d += 64) a += r183[(size_t)b * DM + d] * dw[d];
#pragma unroll
  for (int m = 32; m; m >>= 1) a += __shfl_xor(a, m, 64);
  if (lane == 0) out[(size_t)BATCH * TPF * VOCAB + b] = a + db[0];
}

extern "C" void kernel_launch(void* const* d_in, const int* in_sizes, int n_in,
                              void* d_out, int out_size, void* d_ws, size_t ws_size,
                              hipStream_t stream) {
  const int* ft = (const int*)d_in[0];
  const int* act = (const int*)d_in[1];
  const int* lvl = (const int*)d_in[2];
  const float* tok_emb = (const float*)d_in[3];
  const float* act_emb = (const float*)d_in[4];
  const float* lvl_emb = (const float*)d_in[5];
  const float* ln1_g = (const float*)d_in[6];
  const float* ln1_b = (const float*)d_in[7];
  const float* qkv_w = (const float*)d_in[8];
  const float* qkv_b = (const float*)d_in[9];
  const float* out_w = (const float*)d_in[10];
  const float* out_b = (const float*)d_in[11];
  const float* ln2_g = (const float*)d_in[12];
  const float* ln2_b = (const float*)d_in[13];
  const float* mlp_w1 = (const float*)d_in[14];
  const float* mlp_b1 = (const float*)d_in[15];
  const float* mlp_w2 = (const float*)d_in[16];
  const float* mlp_b2 = (const float*)d_in[17];
  const float* lnf_g = (const float*)d_in[18];
  const float* lnf_b = (const float*)d_in[19];
  const float* head_w = (const float*)d_in[20];
  const float* death_w = (const float*)d_in[21];
  const float* death_b = (const float*)d_in[22];
  const float* rope_cos = (const float*)d_in[23];
  const float* rope_sin = (const float*)d_in[24];

  char* ws = (char*)d_ws;
  size_t off = 0;
  auto alloc = [&](size_t bytes) {
    void* p = ws + off;
    off += (bytes + 255) & ~(size_t)255;
    return p;
  };
  float* x   = (float*)alloc((size_t)NTOK * DM * 4);
  u16* hb    = (u16*)alloc((size_t)NTOK * DM * 2);
  u16* big   = (u16*)alloc((size_t)NTOK * 4096 * 2);
  u16* wq    = (u16*)alloc((size_t)3072 * 1024 * 2);
  u16* wo    = (u16*)alloc((size_t)1024 * 1024 * 2);
  u16* w1    = (u16*)alloc((size_t)4096 * 1024 * 2);
  u16* w2    = (u16*)alloc((size_t)4096 * 1024 * 2);
  u16* pred  = (u16*)alloc((size_t)BATCH * 36 * DM * 2);
  float* r183 = (float*)alloc((size_t)BATCH * DM * 4);

  float* out = (float*)d_out;

  embed_kernel<<<NTOK, 256, 0, stream>>>(ft, act, lvl, tok_emb, act_emb, lvl_emb, x);

  for (int l = 0; l < NLAYER; l++) {
    conv_layer<<<(CN1 + CN2 + 2 * CN3) / 256, 256, 0, stream>>>(
        (const float4*)(qkv_w + (size_t)l * 3072 * 1024), (U16x4*)wq,
        (const float4*)(out_w + (size_t)l * 1024 * 1024), (U16x4*)wo,
        (const float4*)(mlp_w1 + (size_t)l * 4096 * 1024), (U16x4*)w1,
        (const float4*)(mlp_w2 + (size_t)l * 4096 * 1024), (U16x4*)w2);

    ln_rows<<<NTOK / 4, 256, 0, stream>>>(x, ln1_g + l * DM, ln1_b + l * DM, hb, NTOK);
    gemm16<0><<<dim3(3072 / 256, NTOK / 256), 1024, 0, stream>>>(
        hb, wq, qkv_b + (size_t)l * 3072, nullptr, big, 3072, 1024);
    attn_mfma<<<BATCH * NH, 256, 0, stream>>>(big, hb, rope_cos, rope_sin);
    gemm16<1><<<dim3(1024 / 256, NTOK / 256), 1024, 0, stream>>>(
        hb, wo, out_b + (size_t)l * DM, x, nullptr, 1024, 1024);
    ln_rows<<<NTOK / 4, 256, 0, stream>>>(x, ln2_g + l * DM, ln2_b + l * DM, hb, NTOK);
    gemm16<2><<<dim3(4096 / 256, NTOK / 256), 1024, 0, stream>>>(
        hb, w1, mlp_b1 + (size_t)l * 4096, nullptr, big, 4096, 1024);
    gemm16<1><<<dim3(1024 / 256, NTOK / 256), 1024, 0, stream>>>(
        big, w2, mlp_b2 + (size_t)l * DM, x, nullptr, 1024, 4096);
  }

  lnf_kernel<<<BATCH * 37 / 4, 256, 0, stream>>>(x, lnf_g, lnf_b, pred, r183);
  conv_bf16<<<4096 * 1024 / 4 / 256, 256, 0, stream>>>(
      (const float4*)head_w, (U16x4*)w1, 4096 * 1024 / 4);
  gemm16<3><<<dim3(4096 / 256, BATCH * 36 / 256), 1024, 0, stream>>>(
      pred, w1, nullptr, out, nullptr, 4096, 1024);
  death_kernel<<<BATCH, 64, 0, stream>>>(r183, death_w, death_b, out);
}

// Round 13
// 3603.162 us; speedup vs baseline: 1.1586x; 1.0753x over previous
//
#include <hip/hip_runtime.h>
#include <math.h>

#define TPF 36
#define KFRM 4
#define DM 1024
#define NH 16
#define HD 64
#define NLAYER 8
#define VOCAB 4096
#define SEQ 184
#define BATCH 64
#define NTOK (BATCH * SEQ)   // 11776
#define CTXEND 148

typedef unsigned short u16;
typedef unsigned int u32;
typedef __bf16 bf16x8 __attribute__((ext_vector_type(8)));
typedef float f32x4 __attribute__((ext_vector_type(4)));

struct alignas(8) U16x4 { u16 x, y, z, w; };
struct alignas(16) U16x8 { u16 v[8]; };

__device__ inline u16 f2b(float f) {
  u32 u = __float_as_uint(f);
  u += 0x7FFFu + ((u >> 16) & 1u);
  return (u16)(u >> 16);
}
__device__ inline float b2f(u16 h) { return __uint_as_float(((u32)h) << 16); }

// ---------------- f32 -> bf16 conversion ----------------
__global__ __launch_bounds__(256) void conv_bf16(const float4* __restrict__ in,
                                                 U16x4* __restrict__ out, int n4) {
  int i = blockIdx.x * 256 + threadIdx.x;
  if (i >= n4) return;
  float4 v = in[i];
  U16x4 o;
  o.x = f2b(v.x); o.y = f2b(v.y); o.z = f2b(v.z); o.w = f2b(v.w);
  out[i] = o;
}

// fused per-layer conversion: qkv_w + out_w + mlp_w1 + mlp_w2 in one dispatch
#define CN1 (3072 * 1024 / 4)
#define CN2 (1024 * 1024 / 4)
#define CN3 (4096 * 1024 / 4)
__global__ __launch_bounds__(256) void conv_layer(
    const float4* __restrict__ s1, U16x4* __restrict__ d1,
    const float4* __restrict__ s2, U16x4* __restrict__ d2,
    const float4* __restrict__ s3, U16x4* __restrict__ d3,
    const float4* __restrict__ s4, U16x4* __restrict__ d4) {
  int j = blockIdx.x * 256 + threadIdx.x;
  const float4* s; U16x4* d;
  if (j < CN1) { s = s1; d = d1; }
  else if ((j -= CN1) < CN2) { s = s2; d = d2; }
  else if ((j -= CN2) < CN3) { s = s3; d = d3; }
  else { j -= CN3; s = s4; d = d4; }
  float4 v = s[j];
  U16x4 o;
  o.x = f2b(v.x); o.y = f2b(v.y); o.z = f2b(v.z); o.w = f2b(v.w);
  d[j] = o;
}

// ---------------- embedding (float4-vectorized) ----------------
__global__ __launch_bounds__(256) void embed_kernel(
    const int* __restrict__ ft, const int* __restrict__ act, const int* __restrict__ lvl,
    const float* __restrict__ tok_emb, const float* __restrict__ act_emb,
    const float* __restrict__ lvl_emb, float* __restrict__ x) {
  int row = blockIdx.x;
  int b = row / SEQ, s = row % SEQ;
  const float* src;
  if (s < CTXEND) {
    int i = s / 37, r = s % 37;
    if (r < 36) src = tok_emb + (size_t)ft[(b * 5 + i) * TPF + r] * DM;
    else        src = act_emb + (size_t)act[b * KFRM + i] * DM;
  } else {
    src = tok_emb + (size_t)ft[(b * 5 + 4) * TPF + (s - CTXEND)] * DM;
  }
  const float4* s4 = (const float4*)src;
  const float4* l4 = (const float4*)(lvl_emb + (size_t)lvl[b] * DM);
  float4* d4 = (float4*)(x + (size_t)row * DM);
  int t = threadIdx.x;   // DM/4 = 256 = blockDim
  float4 a = s4[t], l = l4[t];
  d4[t] = make_float4(a.x + l.x, a.y + l.y, a.z + l.z, a.w + l.w);
}

// ---------------- LayerNorm (float4-vectorized), one wave per row ----------------
__global__ __launch_bounds__(256) void ln_rows(const float* __restrict__ x,
    const float* __restrict__ g, const float* __restrict__ bb,
    u16* __restrict__ out, int nrows) {
  int wid = blockIdx.x * 4 + (threadIdx.x >> 6);
  if (wid >= nrows) return;
  int lane = threadIdx.x & 63;
  const float4* row = (const float4*)(x + (size_t)wid * DM);
  float4 v[4];
  float s = 0.f, ss = 0.f;
#pragma unroll
  for (int i = 0; i < 4; i++) {
    v[i] = row[i * 64 + lane];
    s += v[i].x + v[i].y + v[i].z + v[i].w;
    ss += v[i].x * v[i].x + v[i].y * v[i].y + v[i].z * v[i].z + v[i].w * v[i].w;
  }
#pragma unroll
  for (int m = 32; m; m >>= 1) { s += __shfl_xor(s, m, 64); ss += __shfl_xor(ss, m, 64); }
  float mean = s * (1.f / DM);
  float var = ss * (1.f / DM) - mean * mean;
  float rstd = rsqrtf(var + 1e-5f);
  const float4* g4 = (const float4*)g;
  const float4* b4 = (const float4*)bb;
  U16x4* dst = (U16x4*)(out + (size_t)wid * DM);
#pragma unroll
  for (int i = 0; i < 4; i++) {
    int c = i * 64 + lane;
    float4 gg = g4[c], bbv = b4[c];
    U16x4 o;
    o.x = f2b((v[i].x - mean) * rstd * gg.x + bbv.x);
    o.y = f2b((v[i].y - mean) * rstd * gg.y + bbv.y);
    o.z = f2b((v[i].z - mean) * rstd * gg.z + bbv.z);
    o.w = f2b((v[i].w - mean) * rstd * gg.w + bbv.w);
    dst[c] = o;
  }
}

// ---------------- final LN (float4-vectorized) ----------------
__global__ __launch_bounds__(256) void lnf_kernel(const float* __restrict__ x,
    const float* __restrict__ g, const float* __restrict__ bb,
    u16* __restrict__ pred, float* __restrict__ r183) {
  int wid = blockIdx.x * 4 + (threadIdx.x >> 6);
  if (wid >= BATCH * 37) return;
  int lane = threadIdx.x & 63;
  int b = wid / 37, si = wid % 37, s = 147 + si;
  const float4* row = (const float4*)(x + ((size_t)b * SEQ + s) * DM);
  float4 v[4];
  float sum = 0.f, ss = 0.f;
#pragma unroll
  for (int i = 0; i < 4; i++) {
    v[i] = row[i * 64 + lane];
    sum += v[i].x + v[i].y + v[i].z + v[i].w;
    ss += v[i].x * v[i].x + v[i].y * v[i].y + v[i].z * v[i].z + v[i].w * v[i].w;
  }
#pragma unroll
  for (int m = 32; m; m >>= 1) { sum += __shfl_xor(sum, m, 64); ss += __shfl_xor(ss, m, 64); }
  float mean = sum * (1.f / DM);
  float var = ss * (1.f / DM) - mean * mean;
  float rstd = rsqrtf(var + 1e-5f);
  const float4* g4 = (const float4*)g;
  const float4* b4 = (const float4*)bb;
  if (s < 183) {
    U16x4* dst = (U16x4*)(pred + ((size_t)b * 36 + si) * DM);
#pragma unroll
    for (int i = 0; i < 4; i++) {
      int c = i * 64 + lane;
      float4 gg = g4[c], bbv = b4[c];
      U16x4 o;
      o.x = f2b((v[i].x - mean) * rstd * gg.x + bbv.x);
      o.y = f2b((v[i].y - mean) * rstd * gg.y + bbv.y);
      o.z = f2b((v[i].z - mean) * rstd * gg.z + bbv.z);
      o.w = f2b((v[i].w - mean) * rstd * gg.w + bbv.w);
      dst[c] = o;
    }
  } else {
    float4* dst = (float4*)(r183 + (size_t)b * DM);
#pragma unroll
    for (int i = 0; i < 4; i++) {
      int c = i * 64 + lane;
      float4 gg = g4[c], bbv = b4[c];
      float4 o;
      o.x = (v[i].x - mean) * rstd * gg.x + bbv.x;
      o.y = (v[i].y - mean) * rstd * gg.y + bbv.y;
      o.z = (v[i].z - mean) * rstd * gg.z + bbv.z;
      o.w = (v[i].w - mean) * rstd * gg.w + bbv.w;
      dst[c] = o;
    }
  }
}

// ---------------- 256x256 bf16 NT GEMM (round-9 champion, untouched) ----------
__device__ inline void gld_lds16(const void* g, void* l) {
  __builtin_amdgcn_global_load_lds((const __attribute__((address_space(1))) void*)g,
                                   (__attribute__((address_space(3))) void*)l, 16, 0, 0);
}

template <int MODE>
__global__ __launch_bounds__(1024) void gemm16(
    const u16* __restrict__ A, const u16* __restrict__ W,
    const float* __restrict__ bias, float* __restrict__ Cf, u16* __restrict__ Cb,
    int M, int Kdim) {
  __shared__ alignas(16) char As[2][32768];
  __shared__ alignas(16) char Bs[2][32768];
  const int tid = threadIdx.x;
  const int wave = tid >> 6, lane = tid & 63;
  const int wm = wave >> 2, wn = wave & 3;
  const int lr = lane & 15, g = lane >> 4;

  const int nbx = gridDim.x;
  int nwg = gridDim.x * gridDim.y;
  int id = blockIdx.y * gridDim.x + blockIdx.x;
  int id2 = (id & 7) * (nwg >> 3) + (id >> 3);
  const int row0 = (id2 / nbx) * 256, col0 = (id2 % nbx) * 256;

  const size_t krow = (size_t)Kdim * 2;
  const char* Abase = (const char*)A + (size_t)row0 * krow;
  const char* Wbase = (const char*)W + (size_t)col0 * krow;

  auto stage = [&](int t, int buf) {
    const char* Ab = Abase + (size_t)t * 128;
    const char* Wb = Wbase + (size_t)t * 128;
#pragma unroll
    for (int c = 0; c < 2; c++) {
      int ob = wave * 2048 + c * 1024;
      int o = ob + lane * 16;
      int os = o ^ (((o >> 7) & 7) << 4);
      gld_lds16(Ab + (size_t)(os >> 7) * krow + (os & 127), &As[buf][ob]);
      gld_lds16(Wb + (size_t)(os >> 7) * krow + (os & 127), &Bs[buf][ob]);
    }
  };

  const int NT = Kdim >> 6;
  f32x4 acc[4][4] = {};

  stage(0, 0);
  __syncthreads();

#pragma unroll 1
  for (int t = 0; t < NT; t++) {
    int p = t & 1;
    if (t + 1 < NT) stage(t + 1, p ^ 1);
#pragma unroll
    for (int kk = 0; kk < 2; kk++) {
      bf16x8 af[4], bfj[4];
#pragma unroll
      for (int i = 0; i < 4; i++) {
        int r = wm * 64 + i * 16 + lr;
        int o = r * 128 + kk * 64 + g * 16;
        af[i] = *(const bf16x8*)(As[p] + (o ^ ((r & 7) << 4)));
      }
#pragma unroll
      for (int j = 0; j < 4; j++) {
        int r = wn * 64 + j * 16 + lr;
        int o = r * 128 + kk * 64 + g * 16;
        bfj[j] = *(const bf16x8*)(Bs[p] + (o ^ ((r & 7) << 4)));
      }
#pragma unroll
      for (int i = 0; i < 4; i++)
#pragma unroll
        for (int j = 0; j < 4; j++)
          acc[i][j] = __builtin_amdgcn_mfma_f32_16x16x32_bf16(af[i], bfj[j], acc[i][j], 0, 0, 0);
    }
    __syncthreads();
  }

  float bj[4];
  if (MODE != 3) {
#pragma unroll
    for (int j = 0; j < 4; j++) bj[j] = bias[col0 + wn * 64 + j * 16 + lr];
  }
#pragma unroll
  for (int i = 0; i < 4; i++) {
#pragma unroll
    for (int j = 0; j < 4; j++) {
#pragma unroll
      for (int r = 0; r < 4; r++) {
        int grow = row0 + wm * 64 + i * 16 + g * 4 + r;
        int gcol = col0 + wn * 64 + j * 16 + lr;
        float v = acc[i][j][r];
        size_t idx = (size_t)grow * M + gcol;
        if (MODE == 0) { v += bj[j]; Cb[idx] = f2b(v); }
        else if (MODE == 1) { v += bj[j]; Cf[idx] += v; }
        else if (MODE == 2) {
          v += bj[j];
          float z = 1.5957692f * (v + 0.044715f * v * v * v);
          v = v / (1.f + __expf(-z));
          Cb[idx] = f2b(v);
        } else {
          Cf[idx] = v;
        }
      }
    }
  }
}

// ---------------- MFMA attention (vectorized staging + fixed LDS layouts) ----------
#define SP 192
#define VST 216
#define PST 216

__device__ inline int block_of(int s) {
  return (s < CTXEND) ? (2 * (s / 37) + ((s % 37) == 36)) : 8;
}

__global__ __launch_bounds__(256) void attn_mfma(const u16* __restrict__ qkv,
    u16* __restrict__ outb, const float* __restrict__ rc, const float* __restrict__ rs) {
  __shared__ alignas(16) char KsB[SP * 128];
  __shared__ alignas(16) u16 Vt[HD][VST];
  __shared__ alignas(16) u16 Ps[4][16][PST];
  const int b = blockIdx.x >> 4, h = blockIdx.x & 15;
  const int tid = threadIdx.x, wave = tid >> 6, lane = tid & 63;
  const int lr = lane & 15, g = lane >> 4, g4 = g * 4;
  const u16* base = qkv + (size_t)b * SEQ * 3072 + h * HD;

  // stage rope'd K: 16B global loads, 16B swizzled LDS stores
  for (int idx = tid; idx < SP * 4; idx += 256) {
    int s = idx >> 2, dq = idx & 3;
    U16x8 v0, v1;
    if (s < SEQ) {
      const u16* kr = base + (size_t)s * 3072 + 1024;
      U16x8 a = *(const U16x8*)(kr + dq * 8);
      U16x8 c8 = *(const U16x8*)(kr + 32 + dq * 8);
#pragma unroll
      for (int j = 0; j < 8; j++) {
        int d = dq * 8 + j;
        float x1 = b2f(a.v[j]), x2 = b2f(c8.v[j]);
        float c = rc[s * 32 + d], sn = rs[s * 32 + d];
        v0.v[j] = f2b(x1 * c - x2 * sn);
        v1.v[j] = f2b(x1 * sn + x2 * c);
      }
    } else {
#pragma unroll
      for (int j = 0; j < 8; j++) { v0.v[j] = 0; v1.v[j] = 0; }
    }
    *(U16x8*)(KsB + ((s * 128 + dq * 16) ^ ((s & 7) << 4))) = v0;
    *(U16x8*)(KsB + ((s * 128 + 64 + dq * 16) ^ ((s & 7) << 4))) = v1;
  }
  // stage V transposed: 16B contiguous global reads, scatter 2B LDS writes
  for (int idx = tid; idx < SP * 8; idx += 256) {
    int k = idx >> 3, d8 = (idx & 7) * 8;
    U16x8 v;
    if (k < SEQ) v = *(const U16x8*)(base + (size_t)k * 3072 + 2048 + d8);
    else {
#pragma unroll
      for (int j = 0; j < 8; j++) v.v[j] = 0;
    }
#pragma unroll
    for (int j = 0; j < 8; j++) Vt[d8 + j][k] = v.v[j];
  }
  __syncthreads();

#pragma unroll 1
  for (int t = 0; t < 3; t++) {
    const int q0 = (wave + 4 * t) * 16;
    const int q_lane = q0 + lr;
    const int qc = (q_lane < SEQ) ? q_lane : (SEQ - 1);

    U16x8 raw0 = *(const U16x8*)(base + (size_t)qc * 3072 + g * 8);
    U16x8 raw1 = *(const U16x8*)(base + (size_t)qc * 3072 + 32 + g * 8);
    bf16x8 qa0, qa1;
#pragma unroll
    for (int i = 0; i < 8; i++) {
      float x1 = b2f(raw0.v[i]), x2 = b2f(raw1.v[i]);
      int di = g * 8 + i;
      float c = rc[qc * 32 + di], sn = rs[qc * 32 + di];
      qa0[i] = (__bf16)(x1 * c - x2 * sn);
      qa1[i] = (__bf16)(x1 * sn + x2 * c);
    }

    f32x4 accs[12];
#pragma unroll
    for (int kt = 0; kt < 12; kt++) accs[kt] = (f32x4){0.f, 0.f, 0.f, 0.f};
#pragma unroll
    for (int kt = 0; kt < 12; kt++) {
      int rt = kt * 16 + lr;
      bf16x8 kb0 = *(const bf16x8*)(KsB + ((rt * 128 + g * 16) ^ ((rt & 7) << 4)));
      bf16x8 kb1 = *(const bf16x8*)(KsB + ((rt * 128 + 64 + g * 16) ^ ((rt & 7) << 4)));
      accs[kt] = __builtin_amdgcn_mfma_f32_16x16x32_bf16(qa0, kb0, accs[kt], 0, 0, 0);
      accs[kt] = __builtin_amdgcn_mfma_f32_16x16x32_bf16(qa1, kb1, accs[kt], 0, 0, 0);
    }

    int qb[4];
#pragma unroll
    for (int r = 0; r < 4; r++) qb[r] = block_of(q0 + g4 + r);
    float mr[4] = {-3e38f, -3e38f, -3e38f, -3e38f};
#pragma unroll
    for (int kt = 0; kt < 12; kt++) {
      int k = kt * 16 + lr;
      bool kv = k < SEQ;
      int kb = kv ? block_of(k) : 9;
#pragma unroll
      for (int r = 0; r < 4; r++) {
        int q = q0 + g4 + r;
        bool ok = kv && (kb <= qb[r]) && !(q >= CTXEND && k >= CTXEND && k > q);
        float s = ok ? accs[kt][r] * 0.125f : -3e38f;
        accs[kt][r] = s;
        mr[r] = fmaxf(mr[r], s);
      }
    }
#pragma unroll
    for (int m = 1; m <= 8; m <<= 1)
#pragma unroll
      for (int r = 0; r < 4; r++) mr[r] = fmaxf(mr[r], __shfl_xor(mr[r], m, 64));

    float sr[4] = {0.f, 0.f, 0.f, 0.f};
#pragma unroll
    for (int kt = 0; kt < 12; kt++) {
#pragma unroll
      for (int r = 0; r < 4; r++) {
        float e = (accs[kt][r] > -1e37f) ? __expf(accs[kt][r] - mr[r]) : 0.f;
        Ps[wave][g4 + r][kt * 16 + lr] = f2b(e);
        sr[r] += e;
      }
    }
#pragma unroll
    for (int m = 1; m <= 8; m <<= 1)
#pragma unroll
      for (int r = 0; r < 4; r++) sr[r] += __shfl_xor(sr[r], m, 64);
    float inv[4];
#pragma unroll
    for (int r = 0; r < 4; r++) inv[r] = 1.f / sr[r];

    __builtin_amdgcn_s_waitcnt(0);

    f32x4 acco[4];
#pragma unroll
    for (int dt = 0; dt < 4; dt++) acco[dt] = (f32x4){0.f, 0.f, 0.f, 0.f};
#pragma unroll
    for (int kc = 0; kc < 6; kc++) {
      bf16x8 pa = *(const bf16x8*)&Ps[wave][lr][kc * 32 + g * 8];
#pragma unroll
      for (int dt = 0; dt < 4; dt++) {
        bf16x8 vb = *(const bf16x8*)&Vt[dt * 16 + lr][kc * 32 + g * 8];
        acco[dt] = __builtin_amdgcn_mfma_f32_16x16x32_bf16(pa, vb, acco[dt], 0, 0, 0);
      }
    }

#pragma unroll
    for (int dt = 0; dt < 4; dt++) {
#pragma unroll
      for (int r = 0; r < 4; r++) {
        int q = q0 + g4 + r;
        if (q < SEQ)
          outb[((size_t)b * SEQ + q) * DM + h * HD + dt * 16 + lr] = f2b(acco[dt][r] * inv[r]);
      }
    }
  }
}

// ---------------- death logit ----------------
__global__ void death_kernel(const float* __restrict__ r183, const float* __restrict__ dw,
                             const float* __restrict__ db, float* __restrict__ out) {
  int b = blockIdx.x, lane = threadIdx.x;
  const float4* r4 = (const float4*)(r183 + (size_t)b * DM);
  const float4* w4 = (const float4*)dw;
  float a = 0.f;
#pragma unroll
  for (int i = 0; i < 4; i++) {
    float4 rv = r4[i * 64 + lane], wv = w4[i * 64 + lane];
    a += rv.x * wv.x + rv.y * wv.y + rv.z * wv.z + rv.w * wv.w;
  }
#pragma unroll
  for (int m = 32; m; m >>= 1) a += __shfl_xor(a, m, 64);
  if (lane == 0) out[(size_t)BATCH * TPF * VOCAB + b] = a + db[0];
}

extern "C" void kernel_launch(void* const* d_in, const int* in_sizes, int n_in,
                              void* d_out, int out_size, void* d_ws, size_t ws_size,
                              hipStream_t stream) {
  const int* ft = (const int*)d_in[0];
  const int* act = (const int*)d_in[1];
  const int* lvl = (const int*)d_in[2];
  const float* tok_emb = (const float*)d_in[3];
  const float* act_emb = (const float*)d_in[4];
  const float* lvl_emb = (const float*)d_in[5];
  const float* ln1_g = (const float*)d_in[6];
  const float* ln1_b = (const float*)d_in[7];
  const float* qkv_w = (const float*)d_in[8];
  const float* qkv_b = (const float*)d_in[9];
  const float* out_w = (const float*)d_in[10];
  const float* out_b = (const float*)d_in[11];
  const float* ln2_g = (const float*)d_in[12];
  const float* ln2_b = (const float*)d_in[13];
  const float* mlp_w1 = (const float*)d_in[14];
  const float* mlp_b1 = (const float*)d_in[15];
  const float* mlp_w2 = (const float*)d_in[16];
  const float* mlp_b2 = (const float*)d_in[17];
  const float* lnf_g = (const float*)d_in[18];
  const float* lnf_b = (const float*)d_in[19];
  const float* head_w = (const float*)d_in[20];
  const float* death_w = (const float*)d_in[21];
  const float* death_b = (const float*)d_in[22];
  const float* rope_cos = (const float*)d_in[23];
  const float* rope_sin = (const float*)d_in[24];

  char* ws = (char*)d_ws;
  size_t off = 0;
  auto alloc = [&](size_t bytes) {
    void* p = ws + off;
    off += (bytes + 255) & ~(size_t)255;
    return p;
  };
  float* x   = (float*)alloc((size_t)NTOK * DM * 4);
  u16* hb    = (u16*)alloc((size_t)NTOK * DM * 2);
  u16* big   = (u16*)alloc((size_t)NTOK * 4096 * 2);
  u16* wq    = (u16*)alloc((size_t)3072 * 1024 * 2);
  u16* wo    = (u16*)alloc((size_t)1024 * 1024 * 2);
  u16* w1    = (u16*)alloc((size_t)4096 * 1024 * 2);
  u16* w2    = (u16*)alloc((size_t)4096 * 1024 * 2);
  u16* pred  = (u16*)alloc((size_t)BATCH * 36 * DM * 2);
  float* r183 = (float*)alloc((size_t)BATCH * DM * 4);

  float* out = (float*)d_out;

  embed_kernel<<<NTOK, 256, 0, stream>>>(ft, act, lvl, tok_emb, act_emb, lvl_emb, x);

  for (int l = 0; l < NLAYER; l++) {
    conv_layer<<<(CN1 + CN2 + 2 * CN3) / 256, 256, 0, stream>>>(
        (const float4*)(qkv_w + (size_t)l * 3072 * 1024), (U16x4*)wq,
        (const float4*)(out_w + (size_t)l * 1024 * 1024), (U16x4*)wo,
        (const float4*)(mlp_w1 + (size_t)l * 4096 * 1024), (U16x4*)w1,
        (const float4*)(mlp_w2 + (size_t)l * 4096 * 1024), (U16x4*)w2);

    ln_rows<<<NTOK / 4, 256, 0, stream>>>(x, ln1_g + l * DM, ln1_b + l * DM, hb, NTOK);
    gemm16<0><<<dim3(3072 / 256, NTOK / 256), 1024, 0, stream>>>(
        hb, wq, qkv_b + (size_t)l * 3072, nullptr, big, 3072, 1024);
    attn_mfma<<<BATCH * NH, 256, 0, stream>>>(big, hb, rope_cos, rope_sin);
    gemm16<1><<<dim3(1024 / 256, NTOK / 256), 1024, 0, stream>>>(
        hb, wo, out_b + (size_t)l * DM, x, nullptr, 1024, 1024);
    ln_rows<<<NTOK / 4, 256, 0, stream>>>(x, ln2_g + l * DM, ln2_b + l * DM, hb, NTOK);
    gemm16<2><<<dim3(4096 / 256, NTOK / 256), 1024, 0, stream>>>(
        hb, w1, mlp_b1 + (size_t)l * 4096, nullptr, big, 4096, 1024);
    gemm16<1><<<dim3(1024 / 256, NTOK / 256), 1024, 0, stream>>>(
        big, w2, mlp_b2 + (size_t)l * DM, x, nullptr, 1024, 4096);
  }

  lnf_kernel<<<BATCH * 37 / 4, 256, 0, stream>>>(x, lnf_g, lnf_b, pred, r183);
  conv_bf16<<<4096 * 1024 / 4 / 256, 256, 0, stream>>>(
      (const float4*)head_w, (U16x4*)w1, 4096 * 1024 / 4);
  gemm16<3><<<dim3(4096 / 256, BATCH * 36 / 256), 1024, 0, stream>>>(
      pred, w1, nullptr, out, nullptr, 4096, 1024);
  death_kernel<<<BATCH, 64, 0, stream>>>(r183, death_w, death_b, out);
}